// Round 7
// baseline (49.271 us; speedup 1.0000x reference)
//
#include <hip/hip_runtime.h>
#include <math.h>

#define BLK 256
#define SLICE 512   // target points staged per block (8 KB LDS as float4)

// pack: p[i] = {x, y, z, 0.5*|p|^2}; also init per-point min slots to +inf.
__global__ void hd_pack_kernel(const float* __restrict__ s1, int n1,
                               const float* __restrict__ s2, int n2,
                               float4* __restrict__ p1, float4* __restrict__ p2,
                               unsigned int* __restrict__ min1,
                               unsigned int* __restrict__ min2) {
    const int i = blockIdx.x * BLK + threadIdx.x;
    if (i < n1) {
        float x = s1[3 * i], y = s1[3 * i + 1], z = s1[3 * i + 2];
        p1[i] = make_float4(x, y, z, 0.5f * fmaf(z, z, fmaf(y, y, x * x)));
        min1[i] = 0x7F800000u;  // +inf bits
    }
    if (i < n2) {
        float x = s2[3 * i], y = s2[3 * i + 1], z = s2[3 * i + 2];
        p2[i] = make_float4(x, y, z, 0.5f * fmaf(z, z, fmaf(y, y, x * x)));
        min2[i] = 0x7F800000u;
    }
}

// min_t |s-t|^2 = 2*(0.5|s|^2 + min_t(0.5|t|^2 - s.t)).
// With sx=-s.x etc: (0.5|t|^2 - s.t) = fma(t.x,sx, fma(t.y,sy, fma(t.z,sz, t.w)))
// -> exactly 3 FMA per pair. Targets broadcast from LDS (all lanes same addr,
// conflict-free). Cross-slice combine via uint atomicMin (d^2 >= 0 so the bit
// pattern preserves float order).
__global__ void hd_min_kernel(const float4* __restrict__ p1, int n1,
                              const float4* __restrict__ p2, int n2,
                              unsigned int* __restrict__ min1,
                              unsigned int* __restrict__ min2) {
    const int dir = blockIdx.z;
    const float4* src = dir ? p2 : p1;
    const float4* tgt = dir ? p1 : p2;
    const int nSrc    = dir ? n2 : n1;
    const int nTgt    = dir ? n1 : n2;
    unsigned int* mout = dir ? min2 : min1;

    const int j0 = blockIdx.y * SLICE;
    if (j0 >= nTgt) return;                    // uniform
    if (blockIdx.x * BLK >= nSrc) return;      // uniform
    const int cnt = min(SLICE, nTgt - j0);

    __shared__ float4 lds[SLICE];
    {
        const float4* g = tgt + j0;            // coalesced 16B/lane
        for (int t = threadIdx.x; t < cnt; t += BLK) lds[t] = g[t];
    }
    __syncthreads();

    const int i = blockIdx.x * BLK + threadIdx.x;
    const bool valid = (i < nSrc);
    float4 s = make_float4(0.f, 0.f, 0.f, 0.f);
    if (valid) s = src[i];
    const float sx = -s.x, sy = -s.y, sz = -s.z;

    float m0 = INFINITY, m1 = INFINITY, m2 = INFINITY, m3 = INFINITY;
    const int c8 = cnt & ~7;
    #pragma unroll 2
    for (int c = 0; c < c8; c += 8) {
        float4 t0 = lds[c + 0];
        float4 t1 = lds[c + 1];
        float4 t2 = lds[c + 2];
        float4 t3 = lds[c + 3];
        float4 t4 = lds[c + 4];
        float4 t5 = lds[c + 5];
        float4 t6 = lds[c + 6];
        float4 t7 = lds[c + 7];
        float v0 = fmaf(t0.x, sx, fmaf(t0.y, sy, fmaf(t0.z, sz, t0.w)));
        float v1 = fmaf(t1.x, sx, fmaf(t1.y, sy, fmaf(t1.z, sz, t1.w)));
        float v2 = fmaf(t2.x, sx, fmaf(t2.y, sy, fmaf(t2.z, sz, t2.w)));
        float v3 = fmaf(t3.x, sx, fmaf(t3.y, sy, fmaf(t3.z, sz, t3.w)));
        float v4 = fmaf(t4.x, sx, fmaf(t4.y, sy, fmaf(t4.z, sz, t4.w)));
        float v5 = fmaf(t5.x, sx, fmaf(t5.y, sy, fmaf(t5.z, sz, t5.w)));
        float v6 = fmaf(t6.x, sx, fmaf(t6.y, sy, fmaf(t6.z, sz, t6.w)));
        float v7 = fmaf(t7.x, sx, fmaf(t7.y, sy, fmaf(t7.z, sz, t7.w)));
        m0 = fminf(m0, fminf(v0, v1));         // -> v_min3_f32
        m1 = fminf(m1, fminf(v2, v3));
        m2 = fminf(m2, fminf(v4, v5));
        m3 = fminf(m3, fminf(v6, v7));
    }
    for (int c = c8; c < cnt; ++c) {           // tail for generic sizes
        float4 t = lds[c];
        m0 = fminf(m0, fmaf(t.x, sx, fmaf(t.y, sy, fmaf(t.z, sz, t.w))));
    }

    const float mv = fminf(fminf(m0, m1), fminf(m2, m3));
    const float d2p = fmaxf(2.0f * (mv + s.w), 0.0f);   // clamp rounding
    if (valid) atomicMin(mout + i, __float_as_uint(d2p));
}

// Single block: both directions' {sum sqrt, max sqrt} + final flag logic.
__global__ void hd_reduce_final(const unsigned int* __restrict__ min1, int n1,
                                const unsigned int* __restrict__ min2, int n2,
                                const int* __restrict__ haus,
                                const int* __restrict__ w12,
                                const int* __restrict__ w21,
                                const int* __restrict__ nout,
                                float* __restrict__ out) {
    __shared__ float ssum[2][BLK / 64], smax[2][BLK / 64];
    for (int dir = 0; dir < 2; ++dir) {
        const unsigned int* mins = dir ? min2 : min1;
        const int n = dir ? n2 : n1;
        float sum = 0.f, mx = 0.f;
        for (int t = threadIdx.x; t < n; t += BLK) {
            float d = sqrtf(__uint_as_float(mins[t]));
            sum += d;
            mx = fmaxf(mx, d);
        }
        for (int o = 32; o > 0; o >>= 1) {
            sum += __shfl_down(sum, o);
            mx = fmaxf(mx, __shfl_down(mx, o));
        }
        const int wid = threadIdx.x >> 6, lid = threadIdx.x & 63;
        if (lid == 0) { ssum[dir][wid] = sum; smax[dir][wid] = mx; }
    }
    __syncthreads();
    if (threadIdx.x == 0) {
        float s12 = 0.f, m12 = 0.f, s21 = 0.f, m21 = 0.f;
        for (int w = 0; w < BLK / 64; ++w) {
            s12 += ssum[0][w]; m12 = fmaxf(m12, smax[0][w]);
            s21 += ssum[1][w]; m21 = fmaxf(m21, smax[1][w]);
        }
        float t12 = 0.f, t21 = 0.f;
        if (*w12 != 0) t12 = (*haus == 0) ? s12 / (float)n1 : m12;
        if (*w21 != 0) t21 = (*haus == 0) ? s21 / (float)n2 : m21;
        if (*nout == 1) {
            out[0] = t12 + t21;
        } else {
            out[0] = t12;
            out[1] = t21;
        }
    }
}

extern "C" void kernel_launch(void* const* d_in, const int* in_sizes, int n_in,
                              void* d_out, int out_size, void* d_ws, size_t ws_size,
                              hipStream_t stream) {
    const float* s1 = (const float*)d_in[0];
    const float* s2 = (const float*)d_in[1];
    const int* haus = (const int*)d_in[2];
    const int* w12  = (const int*)d_in[3];
    const int* w21  = (const int*)d_in[4];
    const int* nout = (const int*)d_in[5];
    float* out = (float*)d_out;

    const int n1 = in_sizes[0] / 3;
    const int n2 = in_sizes[1] / 3;

    // ws layout (16B-aligned base): p1[n1] f4 | p2[n2] f4 | min1[n1] u32 | min2[n2] u32
    float4* p1 = (float4*)d_ws;
    float4* p2 = p1 + n1;
    unsigned int* min1 = (unsigned int*)(p2 + n2);
    unsigned int* min2 = min1 + n1;

    const int maxN = (n1 > n2) ? n1 : n2;
    hd_pack_kernel<<<(maxN + BLK - 1) / BLK, BLK, 0, stream>>>(s1, n1, s2, n2,
                                                               p1, p2, min1, min2);

    dim3 grid((maxN + BLK - 1) / BLK, (maxN + SLICE - 1) / SLICE, 2);
    hd_min_kernel<<<grid, BLK, 0, stream>>>(p1, n1, p2, n2, min1, min2);

    hd_reduce_final<<<1, BLK, 0, stream>>>(min1, n1, min2, n2,
                                           haus, w12, w21, nout, out);
}

// Round 8
// 47.431 us; speedup vs baseline: 1.0388x; 1.0388x over previous
//
#include <hip/hip_runtime.h>
#include <math.h>

#define BLK   256
#define SPT   8     // src points per thread (register-blocked)
#define SLICE 128   // target points staged per block (2 KB LDS)

// pack: p[i] = {x, y, z, 0.5*|p|^2}; also init per-point min slots to +inf.
__global__ void hd_pack_kernel(const float* __restrict__ s1, int n1,
                               const float* __restrict__ s2, int n2,
                               float4* __restrict__ p1, float4* __restrict__ p2,
                               unsigned int* __restrict__ min1,
                               unsigned int* __restrict__ min2) {
    const int i = blockIdx.x * BLK + threadIdx.x;
    if (i < n1) {
        float x = s1[3 * i], y = s1[3 * i + 1], z = s1[3 * i + 2];
        p1[i] = make_float4(x, y, z, 0.5f * fmaf(z, z, fmaf(y, y, x * x)));
        min1[i] = 0x7F800000u;  // +inf bits
    }
    if (i < n2) {
        float x = s2[3 * i], y = s2[3 * i + 1], z = s2[3 * i + 2];
        p2[i] = make_float4(x, y, z, 0.5f * fmaf(z, z, fmaf(y, y, x * x)));
        min2[i] = 0x7F800000u;
    }
}

// min_t |s-t|^2 = 2*(0.5|s|^2 + min_t(0.5|t|^2 - s.t)), and with sx=-s.x etc:
// (0.5|t|^2 - s.t) = fma(t.x,sx, fma(t.y,sy, fma(t.z,sz, t.w))) -> 3 FMA/pair.
// Register-block SPT=8 src points per thread so each broadcast ds_read_b128
// feeds 8 distance chains (24 cyc VALU per 12 cyc LDS issue -> VALU-bound).
// Cross-slice combine via uint atomicMin (d^2 >= 0 preserves float order).
__global__ void hd_min_kernel(const float4* __restrict__ p1, int n1,
                              const float4* __restrict__ p2, int n2,
                              unsigned int* __restrict__ min1,
                              unsigned int* __restrict__ min2) {
    const int dir = blockIdx.z;
    const float4* src = dir ? p2 : p1;
    const float4* tgt = dir ? p1 : p2;
    const int nSrc    = dir ? n2 : n1;
    const int nTgt    = dir ? n1 : n2;
    unsigned int* mout = dir ? min2 : min1;

    const int j0 = blockIdx.y * SLICE;
    const int i0 = blockIdx.x * (BLK * SPT);
    if (j0 >= nTgt) return;                    // uniform
    if (i0 >= nSrc) return;                    // uniform
    const int cnt = min(SLICE, nTgt - j0);

    __shared__ float4 lds[SLICE];
    for (int t = threadIdx.x; t < cnt; t += BLK) lds[t] = tgt[j0 + t];
    __syncthreads();

    // load SPT src points into registers (negated xyz; keep 0.5|s|^2)
    float sx[SPT], sy[SPT], sz[SPT], sw[SPT];
    #pragma unroll
    for (int k = 0; k < SPT; ++k) {
        const int i = i0 + k * BLK + threadIdx.x;
        float4 s = (i < nSrc) ? src[i] : make_float4(0.f, 0.f, 0.f, 0.f);
        sx[k] = -s.x; sy[k] = -s.y; sz[k] = -s.z; sw[k] = s.w;
    }
    float m[SPT];
    #pragma unroll
    for (int k = 0; k < SPT; ++k) m[k] = INFINITY;

    const int c2 = cnt & ~1;
    #pragma unroll 2
    for (int c = 0; c < c2; c += 2) {
        const float4 t0 = lds[c + 0];
        const float4 t1 = lds[c + 1];
        #pragma unroll
        for (int k = 0; k < SPT; ++k) {
            float v0 = fmaf(t0.x, sx[k], fmaf(t0.y, sy[k], fmaf(t0.z, sz[k], t0.w)));
            float v1 = fmaf(t1.x, sx[k], fmaf(t1.y, sy[k], fmaf(t1.z, sz[k], t1.w)));
            m[k] = fminf(m[k], fminf(v0, v1));   // -> v_min3_f32
        }
    }
    if (c2 < cnt) {                              // odd tail
        const float4 t0 = lds[c2];
        #pragma unroll
        for (int k = 0; k < SPT; ++k)
            m[k] = fminf(m[k], fmaf(t0.x, sx[k], fmaf(t0.y, sy[k], fmaf(t0.z, sz[k], t0.w))));
    }

    #pragma unroll
    for (int k = 0; k < SPT; ++k) {
        const int i = i0 + k * BLK + threadIdx.x;
        if (i < nSrc) {
            const float d2p = fmaxf(2.0f * (m[k] + sw[k]), 0.0f);
            atomicMin(mout + i, __float_as_uint(d2p));
        }
    }
}

// Single block: both directions' {sum sqrt, max sqrt} + final flag logic.
__global__ void hd_reduce_final(const unsigned int* __restrict__ min1, int n1,
                                const unsigned int* __restrict__ min2, int n2,
                                const int* __restrict__ haus,
                                const int* __restrict__ w12,
                                const int* __restrict__ w21,
                                const int* __restrict__ nout,
                                float* __restrict__ out) {
    __shared__ float ssum[2][BLK / 64], smax[2][BLK / 64];
    for (int dir = 0; dir < 2; ++dir) {
        const unsigned int* mins = dir ? min2 : min1;
        const int n = dir ? n2 : n1;
        float sum = 0.f, mx = 0.f;
        for (int t = threadIdx.x; t < n; t += BLK) {
            float d = sqrtf(__uint_as_float(mins[t]));
            sum += d;
            mx = fmaxf(mx, d);
        }
        for (int o = 32; o > 0; o >>= 1) {
            sum += __shfl_down(sum, o);
            mx = fmaxf(mx, __shfl_down(mx, o));
        }
        const int wid = threadIdx.x >> 6, lid = threadIdx.x & 63;
        if (lid == 0) { ssum[dir][wid] = sum; smax[dir][wid] = mx; }
    }
    __syncthreads();
    if (threadIdx.x == 0) {
        float s12 = 0.f, m12 = 0.f, s21 = 0.f, m21 = 0.f;
        for (int w = 0; w < BLK / 64; ++w) {
            s12 += ssum[0][w]; m12 = fmaxf(m12, smax[0][w]);
            s21 += ssum[1][w]; m21 = fmaxf(m21, smax[1][w]);
        }
        float t12 = 0.f, t21 = 0.f;
        if (*w12 != 0) t12 = (*haus == 0) ? s12 / (float)n1 : m12;
        if (*w21 != 0) t21 = (*haus == 0) ? s21 / (float)n2 : m21;
        if (*nout == 1) {
            out[0] = t12 + t21;
        } else {
            out[0] = t12;
            out[1] = t21;
        }
    }
}

extern "C" void kernel_launch(void* const* d_in, const int* in_sizes, int n_in,
                              void* d_out, int out_size, void* d_ws, size_t ws_size,
                              hipStream_t stream) {
    const float* s1 = (const float*)d_in[0];
    const float* s2 = (const float*)d_in[1];
    const int* haus = (const int*)d_in[2];
    const int* w12  = (const int*)d_in[3];
    const int* w21  = (const int*)d_in[4];
    const int* nout = (const int*)d_in[5];
    float* out = (float*)d_out;

    const int n1 = in_sizes[0] / 3;
    const int n2 = in_sizes[1] / 3;

    // ws layout (16B-aligned base): p1[n1] f4 | p2[n2] f4 | min1[n1] u32 | min2[n2] u32
    float4* p1 = (float4*)d_ws;
    float4* p2 = p1 + n1;
    unsigned int* min1 = (unsigned int*)(p2 + n2);
    unsigned int* min2 = min1 + n1;

    const int maxN = (n1 > n2) ? n1 : n2;
    hd_pack_kernel<<<(maxN + BLK - 1) / BLK, BLK, 0, stream>>>(s1, n1, s2, n2,
                                                               p1, p2, min1, min2);

    dim3 grid((maxN + BLK * SPT - 1) / (BLK * SPT),
              (maxN + SLICE - 1) / SLICE, 2);
    hd_min_kernel<<<grid, BLK, 0, stream>>>(p1, n1, p2, n2, min1, min2);

    hd_reduce_final<<<1, BLK, 0, stream>>>(min1, n1, min2, n2,
                                           haus, w12, w21, nout, out);
}

// Round 9
// 26.174 us; speedup vs baseline: 1.8824x; 1.8121x over previous
//
#include <hip/hip_runtime.h>
#include <math.h>

#define BLK    256
#define SRCB   32      // src points per block (4 waves x 8 per thread)
#define SPT    8       // src points per thread
#define TILE   512     // target points per LDS tile (8 KB)

// Each block: SRCB src points (one direction) vs ALL targets.
// Wave w (= tid>>6) owns src octet [base + w*8 .. +7]; all 64 lanes of the
// wave hold the SAME 8 src points and cover disjoint target subsets
// (lane-strided), so the per-src min finishes with an in-wave shfl butterfly.
// No global atomics anywhere; block writes one {sum sqrt, max sqrt} partial.
// min_t |s-t|^2 = 2*(0.5|s|^2 + min_t(0.5|t|^2 - s.t)); with negated src the
// inner term is fma(t.x,sx, fma(t.y,sy, fma(t.z,sz, t.w))) -> 3 FMA/pair.
__global__ void __launch_bounds__(BLK, 2)
hd_min_kernel(const float* __restrict__ s1, int n1,
              const float* __restrict__ s2, int n2,
              float2* __restrict__ bpart, int nbx) {
    const int dir = blockIdx.y;
    const float* src = dir ? s2 : s1;
    const float* tgt = dir ? s1 : s2;
    const int nSrc   = dir ? n2 : n1;
    const int nTgt   = dir ? n1 : n2;

    const int w    = threadIdx.x >> 6;     // wave id (0..3)
    const int lane = threadIdx.x & 63;
    const int base = blockIdx.x * SRCB + w * SPT;

    // load SPT src points (negated xyz, +0.5|s|^2); invalid -> zeros (guarded later)
    float sx[SPT], sy[SPT], sz[SPT], sw[SPT];
    #pragma unroll
    for (int k = 0; k < SPT; ++k) {
        const int i = base + k;
        float x = 0.f, y = 0.f, z = 0.f;
        if (i < nSrc) { x = src[3*i]; y = src[3*i+1]; z = src[3*i+2]; }
        sx[k] = -x; sy[k] = -y; sz[k] = -z;
        sw[k] = 0.5f * fmaf(z, z, fmaf(y, y, x * x));
    }

    float m[SPT];
    #pragma unroll
    for (int k = 0; k < SPT; ++k) m[k] = INFINITY;

    __shared__ float4 ldsT[TILE];

    for (int tile = 0; tile < nTgt; tile += TILE) {
        // stage TILE targets as {x,y,z,0.5|t|^2}; padding -> w=+inf (never wins min)
        #pragma unroll
        for (int r = 0; r < TILE / BLK; ++r) {
            const int idx = r * BLK + threadIdx.x;
            const int j = tile + idx;
            float x = 0.f, y = 0.f, z = 0.f, tw;
            if (j < nTgt) {
                x = tgt[3*j]; y = tgt[3*j+1]; z = tgt[3*j+2];
                tw = 0.5f * fmaf(z, z, fmaf(y, y, x * x));
            } else {
                tw = INFINITY;
            }
            ldsT[idx] = make_float4(x, y, z, tw);
        }
        __syncthreads();

        #pragma unroll
        for (int c = 0; c < TILE / 64; ++c) {
            const float4 t = ldsT[c * 64 + lane];   // consecutive b128, conflict-free
            #pragma unroll
            for (int k = 0; k < SPT; ++k) {
                const float v = fmaf(t.x, sx[k], fmaf(t.y, sy[k], fmaf(t.z, sz[k], t.w)));
                m[k] = fminf(m[k], v);
            }
        }
        __syncthreads();
    }

    // in-wave butterfly min: all lanes end with the full-target min per k
    #pragma unroll
    for (int off = 1; off < 64; off <<= 1) {
        #pragma unroll
        for (int k = 0; k < SPT; ++k)
            m[k] = fminf(m[k], __shfl_xor(m[k], off));
    }

    // per-wave {sum sqrt, max sqrt}; then block combine; plain store
    __shared__ float ssum[BLK / 64], smax[BLK / 64];
    if (lane == 0) {
        float sum = 0.f, mx = 0.f;
        #pragma unroll
        for (int k = 0; k < SPT; ++k) {
            if (base + k < nSrc) {
                const float d = sqrtf(fmaxf(2.0f * (m[k] + sw[k]), 0.0f));
                sum += d;
                mx = fmaxf(mx, d);
            }
        }
        ssum[w] = sum; smax[w] = mx;
    }
    __syncthreads();
    if (threadIdx.x == 0) {
        float s = 0.f, mm = 0.f;
        #pragma unroll
        for (int q = 0; q < BLK / 64; ++q) { s += ssum[q]; mm = fmaxf(mm, smax[q]); }
        bpart[dir * nbx + blockIdx.x] = make_float2(s, mm);
    }
}

// Single block: reduce per-block partials for both directions + flag logic.
__global__ void hd_final_kernel(const float2* __restrict__ bpart, int nbx,
                                int n1, int n2,
                                const int* __restrict__ haus,
                                const int* __restrict__ w12,
                                const int* __restrict__ w21,
                                const int* __restrict__ nout,
                                float* __restrict__ out) {
    float s0 = 0.f, x0 = 0.f, s1 = 0.f, x1 = 0.f;
    for (int t = threadIdx.x; t < nbx; t += BLK) {
        const float2 a = bpart[t];
        const float2 b = bpart[nbx + t];
        s0 += a.x; x0 = fmaxf(x0, a.y);
        s1 += b.x; x1 = fmaxf(x1, b.y);
    }
    for (int o = 32; o > 0; o >>= 1) {
        s0 += __shfl_down(s0, o); x0 = fmaxf(x0, __shfl_down(x0, o));
        s1 += __shfl_down(s1, o); x1 = fmaxf(x1, __shfl_down(x1, o));
    }
    __shared__ float a0[BLK/64], b0[BLK/64], a1[BLK/64], b1[BLK/64];
    const int w = threadIdx.x >> 6, lane = threadIdx.x & 63;
    if (lane == 0) { a0[w] = s0; b0[w] = x0; a1[w] = s1; b1[w] = x1; }
    __syncthreads();
    if (threadIdx.x == 0) {
        float S0 = 0.f, X0 = 0.f, S1 = 0.f, X1 = 0.f;
        for (int q = 0; q < BLK/64; ++q) {
            S0 += a0[q]; X0 = fmaxf(X0, b0[q]);
            S1 += a1[q]; X1 = fmaxf(X1, b1[q]);
        }
        float t12 = 0.f, t21 = 0.f;
        if (*w12 != 0) t12 = (*haus == 0) ? S0 / (float)n1 : X0;
        if (*w21 != 0) t21 = (*haus == 0) ? S1 / (float)n2 : X1;
        if (*nout == 1) {
            out[0] = t12 + t21;
        } else {
            out[0] = t12;
            out[1] = t21;
        }
    }
}

extern "C" void kernel_launch(void* const* d_in, const int* in_sizes, int n_in,
                              void* d_out, int out_size, void* d_ws, size_t ws_size,
                              hipStream_t stream) {
    const float* s1 = (const float*)d_in[0];
    const float* s2 = (const float*)d_in[1];
    const int* haus = (const int*)d_in[2];
    const int* w12  = (const int*)d_in[3];
    const int* w21  = (const int*)d_in[4];
    const int* nout = (const int*)d_in[5];
    float* out = (float*)d_out;

    const int n1 = in_sizes[0] / 3;
    const int n2 = in_sizes[1] / 3;
    const int maxN = (n1 > n2) ? n1 : n2;
    const int nbx = (maxN + SRCB - 1) / SRCB;

    float2* bpart = (float2*)d_ws;   // [2][nbx] {sum, max} partials

    dim3 grid(nbx, 2);
    hd_min_kernel<<<grid, BLK, 0, stream>>>(s1, n1, s2, n2, bpart, nbx);

    hd_final_kernel<<<1, BLK, 0, stream>>>(bpart, nbx, n1, n2,
                                           haus, w12, w21, nout, out);
}